// Round 5
// baseline (108.368 us; speedup 1.0000x reference)
//
#include <hip/hip_runtime.h>
#include <hip/hip_bf16.h>

// RBF collocation, N=6144, 17 outputs (closed-form nested JVPs of Gaussian RBF).
// R5 rewrite: MFMA factorization. out_o[i] are fp32-epilogue combos of
//   W = G @ V,  G[i,j] = exp(-0.5*||c_j - p_i||^2)  (bf16),
//   V [N x 21->32 cols] = {v_k, cx*v_k, cz*v_k, ct*v_k, cx^2*v_k, cz^2*v_k}.
// Identities: sum G*(cx-x)*v = W[cx*v] - x*W[v];
//             (cx-x)^2-1 = cx^2 - 2*cx*x + (x^2-1).
// Each lane computes its OWN A-fragment G entries (m=lane&15, k=(lane>>4)*8+i),
// so G never touches LDS/HBM. Dtypes proven R1-R3: inputs fp32, output fp32.

#define NPTS 6144
#define NOUT 17
#define SPLIT 16              // j-chunks; grid = 96*16 = 1536 blocks (6/CU)
#define JC (NPTS / SPLIT)     // 384 j per block
#define NSTEP (JC / 32)       // 12 MFMA K-steps per block

typedef float  f32x4  __attribute__((ext_vector_type(4)));
typedef __bf16 bf16x8 __attribute__((ext_vector_type(8)));

// ws layout (float units):
#define PART_SZ (SPLIT * NPTS * 32)     // 3,145,728 f32 = 12.6 MB
#define CX_OFF PART_SZ
#define CZ_OFF (CX_OFF + NPTS)
#define CT_OFF (CZ_OFF + NPTS)
#define VT_OFF (CT_OFF + NPTS)          // then bf16 Vt[32][NPTS] (16B aligned)

#if defined(__has_builtin) && __has_builtin(__builtin_amdgcn_exp2f)
#define EXP2F(x) __builtin_amdgcn_exp2f(x)
#else
#define EXP2F(x) __expf((x) * 0.6931471805599453f)
#endif

// V-column order (Vt row n holds column n, transposed for contiguous-j loads):
// 0:v1 1:cx*v1 2:cz*v1 | 3:v2 4:cx*v2 5:cz*v2 6:ct*v2 7:cx2*v2 8:cz2*v2
// | 9..14: v3 same 6 | 15..20: v4 same 6 | 21..31: zero pad
__global__ void rbf_prep(const float* __restrict__ cp,
                         const float* __restrict__ v1p,
                         const float* __restrict__ v2p,
                         const float* __restrict__ v3p,
                         const float* __restrict__ v4p,
                         float* __restrict__ cxa, float* __restrict__ cza,
                         float* __restrict__ cta, __bf16* __restrict__ vt) {
  const int j = blockIdx.x * blockDim.x + threadIdx.x;
  if (j >= NPTS) return;
  const float cx = cp[3 * j], cz = cp[3 * j + 1], ct = cp[3 * j + 2];
  cxa[j] = cx; cza[j] = cz; cta[j] = ct;
  const float vv[4] = {v1p[j], v2p[j], v3p[j], v4p[j]};
  vt[0 * NPTS + j] = (__bf16)vv[0];
  vt[1 * NPTS + j] = (__bf16)(cx * vv[0]);
  vt[2 * NPTS + j] = (__bf16)(cz * vv[0]);
#pragma unroll
  for (int k = 0; k < 3; ++k) {         // v2, v3, v4
    const float v = vv[k + 1];
    const int r = 3 + 6 * k;
    vt[(r + 0) * NPTS + j] = (__bf16)v;
    vt[(r + 1) * NPTS + j] = (__bf16)(cx * v);
    vt[(r + 2) * NPTS + j] = (__bf16)(cz * v);
    vt[(r + 3) * NPTS + j] = (__bf16)(ct * v);
    vt[(r + 4) * NPTS + j] = (__bf16)(cx * cx * v);
    vt[(r + 5) * NPTS + j] = (__bf16)(cz * cz * v);
  }
#pragma unroll
  for (int r = 21; r < 32; ++r) vt[r * NPTS + j] = (__bf16)0.f;  // ws is poisoned
}

__global__ __launch_bounds__(256) void rbf_main(
    const float* __restrict__ xp, const float* __restrict__ zp,
    const float* __restrict__ tp,
    const float* __restrict__ cxa, const float* __restrict__ cza,
    const float* __restrict__ cta,
    const __bf16* __restrict__ vt,
    float* __restrict__ part) {
  const int s    = blockIdx.x & (SPLIT - 1);
  const int rb   = blockIdx.x / SPLIT;
  const int w    = threadIdx.x >> 6;
  const int lane = threadIdx.x & 63;
  const int lo   = lane & 15;           // A row within tile / D col / B col
  const int hi   = lane >> 4;           // k-group: lane holds k = hi*8 + i

  const int row = rb * 64 + w * 16 + lo;
  const float xi = xp[row], zi = zp[row], ti = tp[row];

  const __bf16* __restrict__ vb0 = vt + (size_t)lo * NPTS;         // cols 0..15
  const __bf16* __restrict__ vb1 = vt + (size_t)(lo + 16) * NPTS;  // cols 16..31

  f32x4 acc0 = {0.f, 0.f, 0.f, 0.f};
  f32x4 acc1 = {0.f, 0.f, 0.f, 0.f};

  const int jbase = s * JC + hi * 8;
#pragma unroll 2
  for (int step = 0; step < NSTEP; ++step) {
    const int kb = jbase + step * 32;
    const f32x4 cx0 = *(const f32x4*)(cxa + kb);
    const f32x4 cx1 = *(const f32x4*)(cxa + kb + 4);
    const f32x4 cz0 = *(const f32x4*)(cza + kb);
    const f32x4 cz1 = *(const f32x4*)(cza + kb + 4);
    const f32x4 ct0 = *(const f32x4*)(cta + kb);
    const f32x4 ct1 = *(const f32x4*)(cta + kb + 4);
    const bf16x8 b0 = *(const bf16x8*)(vb0 + kb);
    const bf16x8 b1 = *(const bf16x8*)(vb1 + kb);

    bf16x8 af;
#pragma unroll
    for (int i = 0; i < 4; ++i) {
      const float dx = cx0[i] - xi, dz = cz0[i] - zi, dt = ct0[i] - ti;
      const float r2 = fmaf(dx, dx, fmaf(dz, dz, dt * dt));
      af[i] = (__bf16)EXP2F(-0.7213475204444817f * r2);   // exp(-0.5*r2)
    }
#pragma unroll
    for (int i = 0; i < 4; ++i) {
      const float dx = cx1[i] - xi, dz = cz1[i] - zi, dt = ct1[i] - ti;
      const float r2 = fmaf(dx, dx, fmaf(dz, dz, dt * dt));
      af[4 + i] = (__bf16)EXP2F(-0.7213475204444817f * r2);
    }
    acc0 = __builtin_amdgcn_mfma_f32_16x16x32_bf16(af, b0, acc0, 0, 0, 0);
    acc1 = __builtin_amdgcn_mfma_f32_16x16x32_bf16(af, b1, acc1, 0, 0, 0);
  }

  // D layout: col = lane&15, row = (lane>>4)*4 + reg  [guide §3, m89-verified]
#pragma unroll
  for (int reg = 0; reg < 4; ++reg) {
    const int drow = rb * 64 + w * 16 + hi * 4 + reg;
    float* p = part + ((size_t)s * NPTS + drow) * 32;
    p[lo]      = acc0[reg];
    p[lo + 16] = acc1[reg];
  }
}

__global__ __launch_bounds__(256) void rbf_finish(
    const float* __restrict__ part,
    const float* __restrict__ xp, const float* __restrict__ zp,
    const float* __restrict__ tp,
    float* __restrict__ out) {
  const int row = blockIdx.x * 64 + (threadIdx.x >> 2);
  const int q   = threadIdx.x & 3;      // each q sums 4 of the 16 splits

  float wv[24];
#pragma unroll
  for (int o = 0; o < 24; ++o) wv[o] = 0.f;
#pragma unroll
  for (int s4 = 0; s4 < 4; ++s4) {
    const int s = q * 4 + s4;
    const f32x4* p = (const f32x4*)(part + ((size_t)s * NPTS + row) * 32);
#pragma unroll
    for (int c = 0; c < 6; ++c) {
      const f32x4 v = p[c];
      wv[4 * c] += v[0]; wv[4 * c + 1] += v[1];
      wv[4 * c + 2] += v[2]; wv[4 * c + 3] += v[3];
    }
  }
#pragma unroll
  for (int o = 0; o < 21; ++o) {
    wv[o] += __shfl_xor(wv[o], 1, 4);
    wv[o] += __shfl_xor(wv[o], 2, 4);
  }
  if (q == 0) {
    const float x = xp[row], z = zp[row], t = tp[row];
    const float x2 = fmaf(x, x, -1.f), z2 = fmaf(z, z, -1.f);
    float* o = out;
    o[0 * NPTS + row]  = wv[10] - x * wv[9];                         // dudx
    o[1 * NPTS + row]  = wv[11] - z * wv[9];                         // dudz
    o[2 * NPTS + row]  = wv[12] - t * wv[9];                         // dudt
    o[3 * NPTS + row]  = wv[16] - x * wv[15];                        // dwdx
    o[4 * NPTS + row]  = wv[17] - z * wv[15];                        // dwdz
    o[5 * NPTS + row]  = wv[18] - t * wv[15];                        // dwdt
    o[6 * NPTS + row]  = wv[4]  - x * wv[3];                         // dbdx
    o[7 * NPTS + row]  = wv[5]  - z * wv[3];                         // dbdz
    o[8 * NPTS + row]  = wv[6]  - t * wv[3];                         // dbdt
    o[9 * NPTS + row]  = wv[1]  - x * wv[0];                         // dpdx
    o[10 * NPTS + row] = wv[2]  - z * wv[0];                         // dpdz
    o[11 * NPTS + row] = wv[13] - 2.f * x * wv[10] + x2 * wv[9];     // d2u2x
    o[12 * NPTS + row] = wv[14] - 2.f * z * wv[11] + z2 * wv[9];     // d2u2z
    o[13 * NPTS + row] = wv[19] - 2.f * x * wv[16] + x2 * wv[15];    // d2w2x
    o[14 * NPTS + row] = wv[20] - 2.f * z * wv[17] + z2 * wv[15];    // d2w2z
    o[15 * NPTS + row] = wv[7]  - 2.f * x * wv[4]  + x2 * wv[3];     // d2b2x
    o[16 * NPTS + row] = wv[8]  - 2.f * z * wv[5]  + z2 * wv[3];     // d2b2z
  }
}

extern "C" void kernel_launch(void* const* d_in, const int* in_sizes, int n_in,
                              void* d_out, int out_size, void* d_ws, size_t ws_size,
                              hipStream_t stream) {
  const float* xp  = (const float*)d_in[0];
  const float* zp  = (const float*)d_in[1];
  const float* tp  = (const float*)d_in[2];
  const float* cp  = (const float*)d_in[3];
  const float* v1p = (const float*)d_in[4];
  const float* v2p = (const float*)d_in[5];
  const float* v3p = (const float*)d_in[6];
  const float* v4p = (const float*)d_in[7];

  float* ws   = (float*)d_ws;
  float* part = ws;
  float* cxa  = ws + CX_OFF;
  float* cza  = ws + CZ_OFF;
  float* cta  = ws + CT_OFF;
  __bf16* vt  = (__bf16*)(ws + VT_OFF);

  rbf_prep<<<NPTS / 256, 256, 0, stream>>>(cp, v1p, v2p, v3p, v4p,
                                           cxa, cza, cta, vt);

  rbf_main<<<(NPTS / 64) * SPLIT, 256, 0, stream>>>(xp, zp, tp, cxa, cza, cta,
                                                    vt, part);

  rbf_finish<<<NPTS / 64, 256, 0, stream>>>(part, xp, zp, tp, (float*)d_out);
}

// Round 6
// 107.877 us; speedup vs baseline: 1.0045x; 1.0045x over previous
//
#include <hip/hip_runtime.h>
#include <hip/hip_bf16.h>

// RBF collocation, N=6144, 17 outputs (closed-form nested JVPs of Gaussian RBF).
// MFMA factorization (R5, verified): out = linear-epilogue( W = G @ V, x,z,t ),
//   G[i,j] = exp(-0.5*||c_j - p_i||^2)  (bf16 A-fragments, computed in-lane),
//   V [N x 21->32] = {v_k, cx*v_k, cz*v_k, ct*v_k, cx^2*v_k, cz^2*v_k}.
// R6: finish merged into main. Block = 16 rows; 4 waves split K=6144 into
// 4x1536; LDS-reduce W-tile; in-block epilogue writes final outputs.
// Dtypes proven R1-R3: inputs fp32, output fp32.

#define NPTS 6144
#define NSTEP_W 48            // 1536 j per wave / 32 per MFMA step

typedef float  f32x4  __attribute__((ext_vector_type(4)));
typedef __bf16 bf16x8 __attribute__((ext_vector_type(8)));

// ws layout (float units): cxa | cza | cta | Vt[32][NPTS] bf16
#define CX_OFF 0
#define CZ_OFF NPTS
#define CT_OFF (2 * NPTS)
#define VT_OFF (3 * NPTS)     // byte offset 73728, 16B aligned

#if defined(__has_builtin) && __has_builtin(__builtin_amdgcn_exp2f)
#define EXP2F(x) __builtin_amdgcn_exp2f(x)
#else
#define EXP2F(x) __expf((x) * 0.6931471805599453f)
#endif

// V-column order (Vt row n = column n, transposed for contiguous-j loads):
// 0:v1 1:cx*v1 2:cz*v1 | 3:v2 4:cx*v2 5:cz*v2 6:ct*v2 7:cx2*v2 8:cz2*v2
// | 9..14: v3 same 6 | 15..20: v4 same 6 | 21..31: zero pad
__global__ void rbf_prep(const float* __restrict__ cp,
                         const float* __restrict__ v1p,
                         const float* __restrict__ v2p,
                         const float* __restrict__ v3p,
                         const float* __restrict__ v4p,
                         float* __restrict__ cxa, float* __restrict__ cza,
                         float* __restrict__ cta, __bf16* __restrict__ vt) {
  const int j = blockIdx.x * blockDim.x + threadIdx.x;
  if (j >= NPTS) return;
  const float cx = cp[3 * j], cz = cp[3 * j + 1], ct = cp[3 * j + 2];
  cxa[j] = cx; cza[j] = cz; cta[j] = ct;
  const float vv[4] = {v1p[j], v2p[j], v3p[j], v4p[j]};
  vt[0 * NPTS + j] = (__bf16)vv[0];
  vt[1 * NPTS + j] = (__bf16)(cx * vv[0]);
  vt[2 * NPTS + j] = (__bf16)(cz * vv[0]);
#pragma unroll
  for (int k = 0; k < 3; ++k) {         // v2, v3, v4
    const float v = vv[k + 1];
    const int r = 3 + 6 * k;
    vt[(r + 0) * NPTS + j] = (__bf16)v;
    vt[(r + 1) * NPTS + j] = (__bf16)(cx * v);
    vt[(r + 2) * NPTS + j] = (__bf16)(cz * v);
    vt[(r + 3) * NPTS + j] = (__bf16)(ct * v);
    vt[(r + 4) * NPTS + j] = (__bf16)(cx * cx * v);
    vt[(r + 5) * NPTS + j] = (__bf16)(cz * cz * v);
  }
#pragma unroll
  for (int r = 21; r < 32; ++r) vt[r * NPTS + j] = (__bf16)0.f;  // ws is poisoned
}

__global__ __launch_bounds__(256) void rbf_main2(
    const float* __restrict__ xp, const float* __restrict__ zp,
    const float* __restrict__ tp,
    const float* __restrict__ cxa, const float* __restrict__ cza,
    const float* __restrict__ cta,
    const __bf16* __restrict__ vt,
    float* __restrict__ out) {
  __shared__ float lds[4][16][33];      // per-wave W tiles, +1 col pad
  __shared__ float red[16][33];         // reduced W tile

  const int w    = threadIdx.x >> 6;
  const int lane = threadIdx.x & 63;
  const int lo   = lane & 15;           // A row / D col / B col
  const int hi   = lane >> 4;           // k-group: lane holds k = hi*8 + i
  const int rb   = blockIdx.x;          // 0..383, 16 rows each

  const int row = rb * 16 + lo;
  const float xi = xp[row], zi = zp[row], ti = tp[row];

  const __bf16* __restrict__ vb0 = vt + (size_t)lo * NPTS;         // cols 0..15
  const __bf16* __restrict__ vb1 = vt + (size_t)(lo + 16) * NPTS;  // cols 16..31

  f32x4 acc0 = {0.f, 0.f, 0.f, 0.f};
  f32x4 acc1 = {0.f, 0.f, 0.f, 0.f};

  const int jbase = w * (NPTS / 4) + hi * 8;   // wave's K-split + lane k-offset
#pragma unroll 2
  for (int step = 0; step < NSTEP_W; ++step) {
    const int kb = jbase + step * 32;
    const f32x4 cx0 = *(const f32x4*)(cxa + kb);
    const f32x4 cx1 = *(const f32x4*)(cxa + kb + 4);
    const f32x4 cz0 = *(const f32x4*)(cza + kb);
    const f32x4 cz1 = *(const f32x4*)(cza + kb + 4);
    const f32x4 ct0 = *(const f32x4*)(cta + kb);
    const f32x4 ct1 = *(const f32x4*)(cta + kb + 4);
    const bf16x8 b0 = *(const bf16x8*)(vb0 + kb);
    const bf16x8 b1 = *(const bf16x8*)(vb1 + kb);

    bf16x8 af;
#pragma unroll
    for (int i = 0; i < 4; ++i) {
      const float dx = cx0[i] - xi, dz = cz0[i] - zi, dt = ct0[i] - ti;
      const float r2 = fmaf(dx, dx, fmaf(dz, dz, dt * dt));
      af[i] = (__bf16)EXP2F(-0.7213475204444817f * r2);   // exp(-0.5*r2)
    }
#pragma unroll
    for (int i = 0; i < 4; ++i) {
      const float dx = cx1[i] - xi, dz = cz1[i] - zi, dt = ct1[i] - ti;
      const float r2 = fmaf(dx, dx, fmaf(dz, dz, dt * dt));
      af[4 + i] = (__bf16)EXP2F(-0.7213475204444817f * r2);
    }
    acc0 = __builtin_amdgcn_mfma_f32_16x16x32_bf16(af, b0, acc0, 0, 0, 0);
    acc1 = __builtin_amdgcn_mfma_f32_16x16x32_bf16(af, b1, acc1, 0, 0, 0);
  }

  // D layout: col = lane&15, row = (lane>>4)*4 + reg  [m89-verified]
#pragma unroll
  for (int reg = 0; reg < 4; ++reg) {
    const int r = hi * 4 + reg;
    lds[w][r][lo]      = acc0[reg];
    lds[w][r][lo + 16] = acc1[reg];
  }
  __syncthreads();

  // reduce 4 wave-tiles (16x32) with 256 threads, 2 entries each
  {
    const int t = threadIdx.x;
    const int c = t & 31;
    const int r1 = t >> 5;         // 0..7
    const int r2 = 8 + r1;         // 8..15
    red[r1][c] = lds[0][r1][c] + lds[1][r1][c] + lds[2][r1][c] + lds[3][r1][c];
    red[r2][c] = lds[0][r2][c] + lds[1][r2][c] + lds[2][r2][c] + lds[3][r2][c];
  }
  __syncthreads();

  // epilogue: one thread per row (linear combos of W, verified in R5)
  if (threadIdx.x < 16) {
    const int r = threadIdx.x;
    const int orow = rb * 16 + r;
    float wv[21];
#pragma unroll
    for (int c = 0; c < 21; ++c) wv[c] = red[r][c];
    const float x = xp[orow], z = zp[orow], t = tp[orow];
    const float x2 = fmaf(x, x, -1.f), z2 = fmaf(z, z, -1.f);
    float* o = out;
    o[0 * NPTS + orow]  = wv[10] - x * wv[9];                        // dudx
    o[1 * NPTS + orow]  = wv[11] - z * wv[9];                        // dudz
    o[2 * NPTS + orow]  = wv[12] - t * wv[9];                        // dudt
    o[3 * NPTS + orow]  = wv[16] - x * wv[15];                       // dwdx
    o[4 * NPTS + orow]  = wv[17] - z * wv[15];                       // dwdz
    o[5 * NPTS + orow]  = wv[18] - t * wv[15];                       // dwdt
    o[6 * NPTS + orow]  = wv[4]  - x * wv[3];                        // dbdx
    o[7 * NPTS + orow]  = wv[5]  - z * wv[3];                        // dbdz
    o[8 * NPTS + orow]  = wv[6]  - t * wv[3];                        // dbdt
    o[9 * NPTS + orow]  = wv[1]  - x * wv[0];                        // dpdx
    o[10 * NPTS + orow] = wv[2]  - z * wv[0];                        // dpdz
    o[11 * NPTS + orow] = wv[13] - 2.f * x * wv[10] + x2 * wv[9];    // d2u2x
    o[12 * NPTS + orow] = wv[14] - 2.f * z * wv[11] + z2 * wv[9];    // d2u2z
    o[13 * NPTS + orow] = wv[19] - 2.f * x * wv[16] + x2 * wv[15];   // d2w2x
    o[14 * NPTS + orow] = wv[20] - 2.f * z * wv[17] + z2 * wv[15];   // d2w2z
    o[15 * NPTS + orow] = wv[7]  - 2.f * x * wv[4]  + x2 * wv[3];    // d2b2x
    o[16 * NPTS + orow] = wv[8]  - 2.f * z * wv[5]  + z2 * wv[3];    // d2b2z
  }
}

extern "C" void kernel_launch(void* const* d_in, const int* in_sizes, int n_in,
                              void* d_out, int out_size, void* d_ws, size_t ws_size,
                              hipStream_t stream) {
  const float* xp  = (const float*)d_in[0];
  const float* zp  = (const float*)d_in[1];
  const float* tp  = (const float*)d_in[2];
  const float* cp  = (const float*)d_in[3];
  const float* v1p = (const float*)d_in[4];
  const float* v2p = (const float*)d_in[5];
  const float* v3p = (const float*)d_in[6];
  const float* v4p = (const float*)d_in[7];

  float* ws  = (float*)d_ws;
  float* cxa = ws + CX_OFF;
  float* cza = ws + CZ_OFF;
  float* cta = ws + CT_OFF;
  __bf16* vt = (__bf16*)(ws + VT_OFF);

  rbf_prep<<<NPTS / 256, 256, 0, stream>>>(cp, v1p, v2p, v3p, v4p,
                                           cxa, cza, cta, vt);

  rbf_main2<<<NPTS / 16, 256, 0, stream>>>(xp, zp, tp, cxa, cza, cta, vt,
                                           (float*)d_out);
}

// Round 7
// 90.486 us; speedup vs baseline: 1.1976x; 1.1922x over previous
//
#include <hip/hip_runtime.h>
#include <hip/hip_bf16.h>

// RBF collocation, N=6144, 17 outputs (closed-form nested JVPs of Gaussian RBF).
// MFMA factorization (validated R5/R6): out = linear-epilogue( W = G @ V ),
//   G[i,j] = exp(-0.5*||c_j - p_i||^2)  (bf16 A-fragments computed in-lane),
//   V [N x 21->32] = {v_k, cx*v_k, cz*v_k, ct*v_k, cx^2*v_k, cz^2*v_k}.
// R7: fix R6's latency serialization (Occ 12%, VALUBusy 22%, 64-line Vt gathers):
//   - 1536 blocks (6/CU): 96 row-groups x 16 K-splits; wave owns 16 rows.
//   - Vt K-slice staged to LDS coalesced; B-frags via ds_read_b128 (2-way free).
//   - K-partials atomicAdd'ed into d_out (zeroed in prep; epilogue is linear).
// Dtypes proven R1-R3: inputs fp32, output fp32.

#define NPTS 6144
#define NOUTS (17 * NPTS)
#define SPLIT 16
#define KC (NPTS / SPLIT)     // 384 j per block
#define NSTEP (KC / 32)       // 12 MFMA K-steps
#define VROW 392              // padded LDS row stride (bf16): 196 words ≡ 4 mod 32

typedef float  f32x4  __attribute__((ext_vector_type(4)));
typedef __bf16 bf16x8 __attribute__((ext_vector_type(8)));

// ws layout (float units): cxa | cza | cta | Vt[32][NPTS] bf16
#define CX_OFF 0
#define CZ_OFF NPTS
#define CT_OFF (2 * NPTS)
#define VT_OFF (3 * NPTS)

#if defined(__has_builtin) && __has_builtin(__builtin_amdgcn_exp2f)
#define EXP2F(x) __builtin_amdgcn_exp2f(x)
#else
#define EXP2F(x) __expf((x) * 0.6931471805599453f)
#endif

// V-column order: 0:v1 1:cx*v1 2:cz*v1 | 3..8: v2 {1,cx,cz,ct,cx2,cz2}
// | 9..14: v3 same | 15..20: v4 same | 21..31: zero pad
__global__ void rbf_prep(const float* __restrict__ cp,
                         const float* __restrict__ v1p,
                         const float* __restrict__ v2p,
                         const float* __restrict__ v3p,
                         const float* __restrict__ v4p,
                         float* __restrict__ cxa, float* __restrict__ cza,
                         float* __restrict__ cta, __bf16* __restrict__ vt,
                         float* __restrict__ out) {
  const int j = blockIdx.x * blockDim.x + threadIdx.x;
  // zero d_out (poisoned 0xAA each call; main accumulates atomically)
  for (int i = j; i < NOUTS; i += NPTS) out[i] = 0.f;
  const float cx = cp[3 * j], cz = cp[3 * j + 1], ct = cp[3 * j + 2];
  cxa[j] = cx; cza[j] = cz; cta[j] = ct;
  const float vv[4] = {v1p[j], v2p[j], v3p[j], v4p[j]};
  vt[0 * NPTS + j] = (__bf16)vv[0];
  vt[1 * NPTS + j] = (__bf16)(cx * vv[0]);
  vt[2 * NPTS + j] = (__bf16)(cz * vv[0]);
#pragma unroll
  for (int k = 0; k < 3; ++k) {         // v2, v3, v4
    const float v = vv[k + 1];
    const int r = 3 + 6 * k;
    vt[(r + 0) * NPTS + j] = (__bf16)v;
    vt[(r + 1) * NPTS + j] = (__bf16)(cx * v);
    vt[(r + 2) * NPTS + j] = (__bf16)(cz * v);
    vt[(r + 3) * NPTS + j] = (__bf16)(ct * v);
    vt[(r + 4) * NPTS + j] = (__bf16)(cx * cx * v);
    vt[(r + 5) * NPTS + j] = (__bf16)(cz * cz * v);
  }
#pragma unroll
  for (int r = 21; r < 32; ++r) vt[r * NPTS + j] = (__bf16)0.f;
}

__global__ __launch_bounds__(256) void rbf_main3(
    const float* __restrict__ xp, const float* __restrict__ zp,
    const float* __restrict__ tp,
    const float* __restrict__ cxa, const float* __restrict__ cza,
    const float* __restrict__ cta,
    const __bf16* __restrict__ vt,
    float* __restrict__ out) {
  __shared__ __align__(16) unsigned char smem[32 * VROW * 2];  // 25088 B
  __bf16 (*vlds)[VROW] = reinterpret_cast<__bf16(*)[VROW]>(smem);

  const int rg = blockIdx.x % 96;       // row-group (64 rows)
  const int s  = blockIdx.x / 96;       // K-split 0..15
  const int w    = threadIdx.x >> 6;
  const int lane = threadIdx.x & 63;
  const int lo   = lane & 15;           // A row / D col / B col
  const int hi   = lane >> 4;           // k-group: lane holds k = hi*8 + i

  // ---- stage Vt[32][KC] slice into LDS, coalesced 16B chunks ----
  {
    const __bf16* src = vt + s * KC;
#pragma unroll
    for (int it = 0; it < 6; ++it) {    // 32 rows * 48 chunks / 256 threads
      const int idx = threadIdx.x + it * 256;
      const int c = idx / 48, ch = idx % 48;
      *(bf16x8*)&vlds[c][ch * 8] =
          *(const bf16x8*)(src + (size_t)c * NPTS + ch * 8);
    }
  }
  __syncthreads();

  const int rowbase = rg * 64 + w * 16;
  const int row = rowbase + lo;
  const float xi = xp[row], zi = zp[row], ti = tp[row];

  const float* __restrict__ cxg = cxa + s * KC;
  const float* __restrict__ czg = cza + s * KC;
  const float* __restrict__ ctg = cta + s * KC;

  f32x4 acc0 = {0.f, 0.f, 0.f, 0.f};
  f32x4 acc1 = {0.f, 0.f, 0.f, 0.f};

#pragma unroll 2
  for (int step = 0; step < NSTEP; ++step) {
    const int kb = hi * 8 + step * 32;
    const f32x4 cx0 = *(const f32x4*)(cxg + kb);
    const f32x4 cx1 = *(const f32x4*)(cxg + kb + 4);
    const f32x4 cz0 = *(const f32x4*)(czg + kb);
    const f32x4 cz1 = *(const f32x4*)(czg + kb + 4);
    const f32x4 ct0 = *(const f32x4*)(ctg + kb);
    const f32x4 ct1 = *(const f32x4*)(ctg + kb + 4);
    const bf16x8 b0 = *(const bf16x8*)&vlds[lo][kb];        // cols 0..15
    const bf16x8 b1 = *(const bf16x8*)&vlds[lo + 16][kb];   // cols 16..31

    bf16x8 af;
#pragma unroll
    for (int i = 0; i < 4; ++i) {
      const float dx = cx0[i] - xi, dz = cz0[i] - zi, dt = ct0[i] - ti;
      const float r2 = fmaf(dx, dx, fmaf(dz, dz, dt * dt));
      af[i] = (__bf16)EXP2F(-0.7213475204444817f * r2);     // exp(-0.5*r2)
    }
#pragma unroll
    for (int i = 0; i < 4; ++i) {
      const float dx = cx1[i] - xi, dz = cz1[i] - zi, dt = ct1[i] - ti;
      const float r2 = fmaf(dx, dx, fmaf(dz, dz, dt * dt));
      af[4 + i] = (__bf16)EXP2F(-0.7213475204444817f * r2);
    }
    acc0 = __builtin_amdgcn_mfma_f32_16x16x32_bf16(af, b0, acc0, 0, 0, 0);
    acc1 = __builtin_amdgcn_mfma_f32_16x16x32_bf16(af, b1, acc1, 0, 0, 0);
  }

  // ---- wave-private W tile -> LDS (reuse staging area), then epilogue ----
  __syncthreads();                       // all waves done reading vlds
  float* redw = reinterpret_cast<float*>(smem) + w * (16 * 33);
  // D layout: col = lane&15, row = (lane>>4)*4 + reg  [m89-verified]
#pragma unroll
  for (int reg = 0; reg < 4; ++reg) {
    const int r = hi * 4 + reg;
    redw[r * 33 + lo]      = acc0[reg];
    redw[r * 33 + lo + 16] = acc1[reg];
  }
  __syncthreads();

  if (lo < 16 && hi == 0) {              // 16 lanes per wave do 16 rows
    // (guard written as lane<16 via lo/hi to keep it wave-uniform-free)
  }
  if (lane < 16) {
    const int orow = rowbase + lane;
    float wv[21];
#pragma unroll
    for (int c = 0; c < 21; ++c) wv[c] = redw[lane * 33 + c];
    const float x = xp[orow], z = zp[orow], t = tp[orow];
    const float x2 = fmaf(x, x, -1.f), z2 = fmaf(z, z, -1.f);
    float* o = out;
    atomicAdd(&o[0 * NPTS + orow],  wv[10] - x * wv[9]);                     // dudx
    atomicAdd(&o[1 * NPTS + orow],  wv[11] - z * wv[9]);                     // dudz
    atomicAdd(&o[2 * NPTS + orow],  wv[12] - t * wv[9]);                     // dudt
    atomicAdd(&o[3 * NPTS + orow],  wv[16] - x * wv[15]);                    // dwdx
    atomicAdd(&o[4 * NPTS + orow],  wv[17] - z * wv[15]);                    // dwdz
    atomicAdd(&o[5 * NPTS + orow],  wv[18] - t * wv[15]);                    // dwdt
    atomicAdd(&o[6 * NPTS + orow],  wv[4]  - x * wv[3]);                     // dbdx
    atomicAdd(&o[7 * NPTS + orow],  wv[5]  - z * wv[3]);                     // dbdz
    atomicAdd(&o[8 * NPTS + orow],  wv[6]  - t * wv[3]);                     // dbdt
    atomicAdd(&o[9 * NPTS + orow],  wv[1]  - x * wv[0]);                     // dpdx
    atomicAdd(&o[10 * NPTS + orow], wv[2]  - z * wv[0]);                     // dpdz
    atomicAdd(&o[11 * NPTS + orow], wv[13] - 2.f * x * wv[10] + x2 * wv[9]); // d2u2x
    atomicAdd(&o[12 * NPTS + orow], wv[14] - 2.f * z * wv[11] + z2 * wv[9]); // d2u2z
    atomicAdd(&o[13 * NPTS + orow], wv[19] - 2.f * x * wv[16] + x2 * wv[15]);// d2w2x
    atomicAdd(&o[14 * NPTS + orow], wv[20] - 2.f * z * wv[17] + z2 * wv[15]);// d2w2z
    atomicAdd(&o[15 * NPTS + orow], wv[7]  - 2.f * x * wv[4]  + x2 * wv[3]); // d2b2x
    atomicAdd(&o[16 * NPTS + orow], wv[8]  - 2.f * z * wv[5]  + z2 * wv[3]); // d2b2z
  }
}

extern "C" void kernel_launch(void* const* d_in, const int* in_sizes, int n_in,
                              void* d_out, int out_size, void* d_ws, size_t ws_size,
                              hipStream_t stream) {
  const float* xp  = (const float*)d_in[0];
  const float* zp  = (const float*)d_in[1];
  const float* tp  = (const float*)d_in[2];
  const float* cp  = (const float*)d_in[3];
  const float* v1p = (const float*)d_in[4];
  const float* v2p = (const float*)d_in[5];
  const float* v3p = (const float*)d_in[6];
  const float* v4p = (const float*)d_in[7];

  float* ws  = (float*)d_ws;
  float* cxa = ws + CX_OFF;
  float* cza = ws + CZ_OFF;
  float* cta = ws + CT_OFF;
  __bf16* vt = (__bf16*)(ws + VT_OFF);

  rbf_prep<<<NPTS / 256, 256, 0, stream>>>(cp, v1p, v2p, v3p, v4p,
                                           cxa, cza, cta, vt, (float*)d_out);

  rbf_main3<<<96 * SPLIT, 256, 0, stream>>>(xp, zp, tp, cxa, cza, cta, vt,
                                            (float*)d_out);
}